// Round 1
// baseline (2285.092 us; speedup 1.0000x reference)
//
#include <hip/hip_runtime.h>
#include <math.h>

#define NB 16384
#define NT 13
#define NDIN 4
#define NL 48
#define NE 60
#define ND 30
#define MB 16

__device__ __forceinline__ float sigmf(float v) { return 1.0f / (1.0f + expf(-v)); }

__global__ __launch_bounds__(256, 2) void decoder_kernel(
    const float* __restrict__ y,      // [B,13,4]
    const float* __restrict__ enc,    // [48,B,60]
    const float* __restrict__ hidden, // [B,30]
    const float* __restrict__ Wv, const float* __restrict__ bv,
    const float* __restrict__ Wg, const float* __restrict__ bg,
    const float* __restrict__ Wf1, const float* __restrict__ bf1,
    const float* __restrict__ Wf2, const float* __restrict__ bf2,
    const float* __restrict__ Wf3, const float* __restrict__ bf3,
    const float* __restrict__ Wih, const float* __restrict__ bih,
    const float* __restrict__ Whh, const float* __restrict__ bhh,
    float* __restrict__ out)          // [12,B]
{
    // ---- LDS: weights transposed ([k][j]) so lanes (consecutive j) hit
    // consecutive addresses; LSTM weights interleaved [k][j][gate] -> b128.
    __shared__ float s_WvT[NE * ND];                    // [e][j]
    __shared__ float s_WgT[2 * ND * ND];                // [k][j], k<60 over [h|V]
    __shared__ __align__(16) float s_Wih4[34 * ND * 4]; // [k][j][g] g=i,f,g,o
    __shared__ __align__(16) float s_Whh4[ND * ND * 4]; // [k][j][g]
    __shared__ float s_Wf1T[31 * ND];                   // [k][j]
    __shared__ float s_Wf2T[ND * 15];                   // [k][j]
    __shared__ float s_Wf3[16];
    __shared__ float s_bv[ND], s_bg[ND], s_bf1[ND], s_bf2[16];
    __shared__ __align__(16) float s_b4[ND * 4];        // [j][g] = b_ih+b_hh
    __shared__ float s_bf3;
    __shared__ float s_h[2][MB][ND];                    // double-buffered hidden
    __shared__ float s_V[MB][ND];
    // union region: phase1 uses it as es[16][60] (960 floats); decode phase
    // uses it as x[16][34] | z1[16][30] | z2[16][15] (1264 floats).
    __shared__ __align__(16) float s_u[MB * 34 + MB * ND + MB * 15];

    const int t = threadIdx.x;
    const int b0 = blockIdx.x * MB;

    // ---- stage weights (transposed); tiny (52KB), L2-resident across blocks
    for (int d = t; d < NE * ND; d += 256) { int e = d / ND, j = d - e * ND; s_WvT[d] = Wv[j * NE + e]; }
    for (int d = t; d < 2 * ND * ND; d += 256) { int k = d / ND, j = d - k * ND; s_WgT[d] = Wg[j * (2 * ND) + k]; }
    for (int d = t; d < 34 * ND * 4; d += 256) { int g = d & 3, kj = d >> 2, k = kj / ND, j = kj - k * ND; s_Wih4[d] = Wih[(g * ND + j) * 34 + k]; }
    for (int d = t; d < ND * ND * 4; d += 256) { int g = d & 3, kj = d >> 2, k = kj / ND, j = kj - k * ND; s_Whh4[d] = Whh[(g * ND + j) * ND + k]; }
    for (int d = t; d < 31 * ND; d += 256) { int k = d / ND, j = d - k * ND; s_Wf1T[d] = Wf1[j * 31 + k]; }
    for (int d = t; d < ND * 15; d += 256) { int k = d / 15, j = d - k * 15; s_Wf2T[d] = Wf2[j * ND + k]; }
    if (t < 15) s_Wf3[t] = Wf3[t];
    if (t < ND) { s_bv[t] = bv[t]; s_bg[t] = bg[t]; s_bf1[t] = bf1[t]; }
    if (t < 15) s_bf2[t] = bf2[t];
    if (t == 0) s_bf3 = bf3[0];
    if (t < ND * 4) { int g = t & 3, j = t >> 2; s_b4[t] = bih[g * ND + j] + bhh[g * ND + j]; }

    // ---- phase 1: enc_spatial mean over L (coalesced float4 streaming)
    if (t < 240) {
        const float4* e4 = (const float4*)enc;
        const long base = (long)b0 * (NE / 4) + t;   // float4 units
        float sx = 0.f, sy = 0.f, sz = 0.f, sw = 0.f;
        #pragma unroll
        for (int l = 0; l < NL; ++l) {
            float4 v = e4[(long)l * (NB * NE / 4) + base];
            sx += v.x; sy += v.y; sz += v.z; sw += v.w;
        }
        const float sc = 1.0f / 48.0f;
        float4 r; r.x = sx * sc; r.y = sy * sc; r.z = sz * sc; r.w = sw * sc;
        ((float4*)s_u)[t] = r;    // es[16][60]
    }
    // h init
    for (int d = t; d < MB * ND; d += 256) { int b = d / ND, j = d - b * ND; s_h[0][b][j] = hidden[(long)(b0 + b) * ND + j]; }
    __syncthreads();

    // ---- V = es @ Wv.T + bv   (attention context is exactly V: softmax over
    // a singleton axis is 1.0, so Q/K/scores/step-feature are dead code)
    if (t < 240) {
        const int j = t % ND, b = t / ND;
        float v1 = s_bv[j], v2 = v1;
        const float* es1 = s_u + b * NE;
        const float* es2 = s_u + (b + 8) * NE;
        #pragma unroll
        for (int e = 0; e < NE; ++e) {
            float w = s_WvT[e * ND + j];
            v1 += w * es1[e]; v2 += w * es2[e];
        }
        s_V[b][j] = v1; s_V[b + 8][j] = v2;
    }
    __syncthreads();

    // ---- rin0 = nan_to_num(y[:,0,:])  (overwrites es region)
    float* x  = s_u;                 // [16][34]  x = [rin(4) | enh(30)]
    float* z1 = s_u + MB * 34;       // [16][30]
    float* z2 = z1 + MB * ND;        // [16][15]
    if (t < MB) {
        const float* yb = y + (long)(b0 + t) * (NT * NDIN);
        #pragma unroll
        for (int d = 0; d < 4; ++d) {
            float v = yb[d];
            x[t * 34 + d] = (v == v) ? v : 0.0f;
        }
    }
    __syncthreads();

    float c1 = 0.0f, c2 = 0.0f;      // cell state lives in registers
    int cur = 0;
    for (int i = 1; i <= 12; ++i) {
        const float se = (float)i / 12.0f;

        // ---- A: gate = sigmoid([h|V]@Wg.T+bg); enh -> x[:,4+j]
        if (t < 240) {
            const int j = t % ND, b = t / ND;
            const float* h1 = &s_h[cur][b][0];
            const float* h2 = &s_h[cur][b + 8][0];
            const float* v1p = &s_V[b][0];
            const float* v2p = &s_V[b + 8][0];
            float a1 = s_bg[j], a2 = s_bg[j];
            #pragma unroll
            for (int k = 0; k < ND; ++k) {
                float w = s_WgT[k * ND + j];
                a1 += w * h1[k]; a2 += w * h2[k];
            }
            #pragma unroll
            for (int k = 0; k < ND; ++k) {
                float w = s_WgT[(ND + k) * ND + j];
                a1 += w * v1p[k]; a2 += w * v2p[k];
            }
            const float g1 = sigmf(a1), g2 = sigmf(a2);
            x[b * 34 + 4 + j]        = g1 * h1[j] + (1.0f - g1) * v1p[j];
            x[(b + 8) * 34 + 4 + j]  = g2 * h2[j] + (1.0f - g2) * v2p[j];
        }
        __syncthreads();

        // ---- B: LSTM cell. g = x@W_ih.T + h@W_hh.T + (b_ih+b_hh)
        if (t < 240) {
            const int j = t % ND, b = t / ND;
            const float4 bb = ((const float4*)s_b4)[j];
            float i1 = bb.x, f1 = bb.y, g1 = bb.z, o1 = bb.w;
            float i2 = bb.x, f2 = bb.y, g2 = bb.z, o2 = bb.w;
            #pragma unroll
            for (int k = 0; k < 34; ++k) {
                const float4 w = ((const float4*)s_Wih4)[k * ND + j];
                const float x1 = x[b * 34 + k], x2 = x[(b + 8) * 34 + k];
                i1 += w.x * x1; f1 += w.y * x1; g1 += w.z * x1; o1 += w.w * x1;
                i2 += w.x * x2; f2 += w.y * x2; g2 += w.z * x2; o2 += w.w * x2;
            }
            #pragma unroll
            for (int k = 0; k < ND; ++k) {
                const float4 w = ((const float4*)s_Whh4)[k * ND + j];
                const float h1 = s_h[cur][b][k], h2 = s_h[cur][b + 8][k];
                i1 += w.x * h1; f1 += w.y * h1; g1 += w.z * h1; o1 += w.w * h1;
                i2 += w.x * h2; f2 += w.y * h2; g2 += w.z * h2; o2 += w.w * h2;
            }
            const float cn1 = sigmf(f1) * c1 + sigmf(i1) * tanhf(g1);
            const float cn2 = sigmf(f2) * c2 + sigmf(i2) * tanhf(g2);
            c1 = cn1; c2 = cn2;
            s_h[cur ^ 1][b][j]     = sigmf(o1) * tanhf(cn1);
            s_h[cur ^ 1][b + 8][j] = sigmf(o2) * tanhf(cn2);
        }
        __syncthreads();

        // ---- C: z1 = relu([h_new|se]@Wf1.T + bf1)
        if (t < 240) {
            const int j = t % ND, b = t / ND;
            const float base = s_bf1[j] + se * s_Wf1T[ND * ND + j];
            float a1 = base, a2 = base;
            const float* hn1 = &s_h[cur ^ 1][b][0];
            const float* hn2 = &s_h[cur ^ 1][b + 8][0];
            #pragma unroll
            for (int k = 0; k < ND; ++k) {
                float w = s_Wf1T[k * ND + j];
                a1 += w * hn1[k]; a2 += w * hn2[k];
            }
            z1[b * ND + j]       = fmaxf(a1, 0.0f);
            z1[(b + 8) * ND + j] = fmaxf(a2, 0.0f);
        }
        __syncthreads();

        // ---- D: z2 = relu(z1@Wf2.T + bf2)
        if (t < 240) {
            const int j = t % 15, b = t / 15;
            float a = s_bf2[j];
            #pragma unroll
            for (int k = 0; k < ND; ++k) a += s_Wf2T[k * 15 + j] * z1[b * ND + k];
            z2[b * 15 + j] = fmaxf(a, 0.0f);
        }
        __syncthreads();

        // ---- E: out = z2@Wf3.T + bf3; rin_next = [y[:,i,1:4], out]
        if (t < MB) {
            const int b = t;
            float o = s_bf3;
            #pragma unroll
            for (int k = 0; k < 15; ++k) o += s_Wf3[k] * z2[b * 15 + k];
            out[(long)(i - 1) * NB + b0 + b] = o;
            const float* yb = y + (long)(b0 + b) * (NT * NDIN) + i * NDIN;
            x[b * 34 + 0] = yb[1];
            x[b * 34 + 1] = yb[2];
            x[b * 34 + 2] = yb[3];
            x[b * 34 + 3] = o;
        }
        __syncthreads();
        cur ^= 1;
    }
}

extern "C" void kernel_launch(void* const* d_in, const int* in_sizes, int n_in,
                              void* d_out, int out_size, void* d_ws, size_t ws_size,
                              hipStream_t stream) {
    (void)in_sizes; (void)n_in; (void)out_size; (void)d_ws; (void)ws_size;
    // setup_inputs order:
    // 0 batch_ids, 1 y, 2 encoder_outputs, 3 hidden, 4 Wq, 5 bq, 6 Wk, 7 bk,
    // 8 Wv, 9 bv, 10 Wsa1, 11 bsa1, 12 Wsa2, 13 bsa2, 14 Wg, 15 bg,
    // 16 Wf1, 17 bf1, 18 Wf2, 19 bf2, 20 Wf3, 21 bf3, 22 W_ih, 23 b_ih,
    // 24 W_hh, 25 b_hh.   (Wq/bq/Wk/bk/Wsa* are dead: softmax over size-1 axis == 1)
    const float* y   = (const float*)d_in[1];
    const float* enc = (const float*)d_in[2];
    const float* hid = (const float*)d_in[3];
    const float* Wv  = (const float*)d_in[8];
    const float* bv  = (const float*)d_in[9];
    const float* Wg  = (const float*)d_in[14];
    const float* bg  = (const float*)d_in[15];
    const float* Wf1 = (const float*)d_in[16];
    const float* bf1 = (const float*)d_in[17];
    const float* Wf2 = (const float*)d_in[18];
    const float* bf2 = (const float*)d_in[19];
    const float* Wf3 = (const float*)d_in[20];
    const float* bf3 = (const float*)d_in[21];
    const float* Wih = (const float*)d_in[22];
    const float* bih = (const float*)d_in[23];
    const float* Whh = (const float*)d_in[24];
    const float* bhh = (const float*)d_in[25];
    float* out = (float*)d_out;

    decoder_kernel<<<dim3(NB / MB), dim3(256), 0, stream>>>(
        y, enc, hid, Wv, bv, Wg, bg, Wf1, bf1, Wf2, bf2, Wf3, bf3,
        Wih, bih, Whh, bhh, out);
}

// Round 2
// 173.859 us; speedup vs baseline: 13.1434x; 13.1434x over previous
//
#include <hip/hip_runtime.h>
#include <math.h>

#define NB 16384
#define NT 13
#define NDIN 4
#define NL 48
#define NE 60
#define ND 30
#define MB 16

// Guaranteed-inline HW transcendentals: v_exp_f32 + v_rcp_f32.
// sigmoid(v): v->-inf: exp(inf)=inf -> rcp(inf)=0 OK; v->+inf: rcp(1)=1 OK.
// tanh(v) = 1 - 2/(e^{2v}+1): v->+inf -> 1; v->-inf -> -1. ~1e-6 added error.
__device__ __forceinline__ float fast_sig(float v) {
    return __builtin_amdgcn_rcpf(1.0f + __expf(-v));
}
__device__ __forceinline__ float fast_tanh(float v) {
    return 1.0f - 2.0f * __builtin_amdgcn_rcpf(1.0f + __expf(2.0f * v));
}

__global__ __launch_bounds__(256, 2) void decoder_kernel(
    const float* __restrict__ y,      // [B,13,4]
    const float* __restrict__ enc,    // [48,B,60]
    const float* __restrict__ hidden, // [B,30]
    const float* __restrict__ Wv, const float* __restrict__ bv,
    const float* __restrict__ Wg, const float* __restrict__ bg,
    const float* __restrict__ Wf1, const float* __restrict__ bf1,
    const float* __restrict__ Wf2, const float* __restrict__ bf2,
    const float* __restrict__ Wf3, const float* __restrict__ bf3,
    const float* __restrict__ Wih, const float* __restrict__ bih,
    const float* __restrict__ Whh, const float* __restrict__ bhh,
    float* __restrict__ out)          // [12,B]
{
    __shared__ float s_WvT[NE * ND];                    // [e][j]
    __shared__ float s_WgT[2 * ND * ND];                // [k][j]
    __shared__ __align__(16) float s_Wih4[34 * ND * 4]; // [k][j][g] g=i,f,g,o
    __shared__ __align__(16) float s_Whh4[ND * ND * 4]; // [k][j][g]
    __shared__ float s_Wf1T[31 * ND];                   // [k][j]
    __shared__ float s_Wf2T[ND * 15];                   // [k][j]
    __shared__ float s_Wf3[16];
    __shared__ float s_bv[ND], s_bg[ND], s_bf1[ND], s_bf2[16];
    __shared__ __align__(16) float s_b4[ND * 4];        // [j][g] = b_ih+b_hh
    __shared__ float s_bf3;
    __shared__ float s_h[2][MB][ND];                    // double-buffered hidden
    __shared__ float s_V[MB][ND];
    // union: phase1 es[16][60]; decode x[16][34] | z1[16][30] | z2[16][15]
    __shared__ __align__(16) float s_u[MB * 34 + MB * ND + MB * 15];

    const int t = threadIdx.x;
    const int b0 = blockIdx.x * MB;

    // ---- stage weights (transposed)
    for (int d = t; d < NE * ND; d += 256) { int e = d / ND, j = d - e * ND; s_WvT[d] = Wv[j * NE + e]; }
    for (int d = t; d < 2 * ND * ND; d += 256) { int k = d / ND, j = d - k * ND; s_WgT[d] = Wg[j * (2 * ND) + k]; }
    for (int d = t; d < 34 * ND * 4; d += 256) { int g = d & 3, kj = d >> 2, k = kj / ND, j = kj - k * ND; s_Wih4[d] = Wih[(g * ND + j) * 34 + k]; }
    for (int d = t; d < ND * ND * 4; d += 256) { int g = d & 3, kj = d >> 2, k = kj / ND, j = kj - k * ND; s_Whh4[d] = Whh[(g * ND + j) * ND + k]; }
    for (int d = t; d < 31 * ND; d += 256) { int k = d / ND, j = d - k * ND; s_Wf1T[d] = Wf1[j * 31 + k]; }
    for (int d = t; d < ND * 15; d += 256) { int k = d / 15, j = d - k * 15; s_Wf2T[d] = Wf2[j * ND + k]; }
    if (t < 15) s_Wf3[t] = Wf3[t];
    if (t < ND) { s_bv[t] = bv[t]; s_bg[t] = bg[t]; s_bf1[t] = bf1[t]; }
    if (t < 15) s_bf2[t] = bf2[t];
    if (t == 0) s_bf3 = bf3[0];
    if (t < ND * 4) { int g = t & 3, j = t >> 2; s_b4[t] = bih[g * ND + j] + bhh[g * ND + j]; }

    // ---- phase 1: enc_spatial mean over L (coalesced float4, bounded unroll)
    if (t < 240) {
        const float4* e4 = (const float4*)enc;
        const long base = (long)b0 * (NE / 4) + t;   // float4 units
        float sx = 0.f, sy = 0.f, sz = 0.f, sw = 0.f;
        #pragma unroll 4
        for (int l = 0; l < NL; ++l) {
            float4 v = e4[(long)l * (NB * NE / 4) + base];
            sx += v.x; sy += v.y; sz += v.z; sw += v.w;
        }
        const float sc = 1.0f / 48.0f;
        float4 r; r.x = sx * sc; r.y = sy * sc; r.z = sz * sc; r.w = sw * sc;
        ((float4*)s_u)[t] = r;    // es[16][60]
    }
    for (int d = t; d < MB * ND; d += 256) { int b = d / ND, j = d - b * ND; s_h[0][b][j] = hidden[(long)(b0 + b) * ND + j]; }
    __syncthreads();

    // ---- V = es @ Wv.T + bv  (softmax over singleton axis == 1 -> context = V)
    if (t < 240) {
        const int j = t % ND, b = t / ND;
        float v1 = s_bv[j], v2 = v1;
        const float* es1 = s_u + b * NE;
        const float* es2 = s_u + (b + 8) * NE;
        #pragma unroll
        for (int e = 0; e < NE; ++e) {
            float w = s_WvT[e * ND + j];
            v1 += w * es1[e]; v2 += w * es2[e];
        }
        s_V[b][j] = v1; s_V[b + 8][j] = v2;
    }
    __syncthreads();

    // ---- rin0 = nan_to_num(y[:,0,:])  (overwrites es region)
    float* x  = s_u;                 // [16][34]  x = [rin(4) | enh(30)]
    float* z1 = s_u + MB * 34;       // [16][30]
    float* z2 = z1 + MB * ND;        // [16][15]
    if (t < MB) {
        const float* yb = y + (long)(b0 + t) * (NT * NDIN);
        #pragma unroll
        for (int d = 0; d < 4; ++d) {
            float v = yb[d];
            x[t * 34 + d] = (v == v) ? v : 0.0f;
        }
    }
    __syncthreads();

    float c1 = 0.0f, c2 = 0.0f;      // cell state in registers
    int cur = 0;
    #pragma unroll 1                 // keep the step body small: no giant
    for (int i = 1; i <= 12; ++i) {  // unrolled region -> no spill, I$-resident
        const float se = (float)i / 12.0f;

        // ---- A: gate = sigmoid([h|V]@Wg.T+bg); enh -> x[:,4+j]
        if (t < 240) {
            const int j = t % ND, b = t / ND;
            const float* h1 = &s_h[cur][b][0];
            const float* h2 = &s_h[cur][b + 8][0];
            const float* v1p = &s_V[b][0];
            const float* v2p = &s_V[b + 8][0];
            float a1 = s_bg[j], a2 = s_bg[j];
            #pragma unroll
            for (int k = 0; k < ND; ++k) {
                float w = s_WgT[k * ND + j];
                a1 += w * h1[k]; a2 += w * h2[k];
            }
            #pragma unroll
            for (int k = 0; k < ND; ++k) {
                float w = s_WgT[(ND + k) * ND + j];
                a1 += w * v1p[k]; a2 += w * v2p[k];
            }
            const float g1 = fast_sig(a1), g2 = fast_sig(a2);
            x[b * 34 + 4 + j]        = g1 * h1[j] + (1.0f - g1) * v1p[j];
            x[(b + 8) * 34 + 4 + j]  = g2 * h2[j] + (1.0f - g2) * v2p[j];
        }
        __syncthreads();

        // ---- B: LSTM cell. g = x@W_ih.T + h@W_hh.T + (b_ih+b_hh)
        if (t < 240) {
            const int j = t % ND, b = t / ND;
            const float4 bb = ((const float4*)s_b4)[j];
            float i1 = bb.x, f1 = bb.y, g1 = bb.z, o1 = bb.w;
            float i2 = bb.x, f2 = bb.y, g2 = bb.z, o2 = bb.w;
            #pragma unroll
            for (int k = 0; k < 34; ++k) {
                const float4 w = ((const float4*)s_Wih4)[k * ND + j];
                const float x1 = x[b * 34 + k], x2 = x[(b + 8) * 34 + k];
                i1 += w.x * x1; f1 += w.y * x1; g1 += w.z * x1; o1 += w.w * x1;
                i2 += w.x * x2; f2 += w.y * x2; g2 += w.z * x2; o2 += w.w * x2;
            }
            #pragma unroll
            for (int k = 0; k < ND; ++k) {
                const float4 w = ((const float4*)s_Whh4)[k * ND + j];
                const float h1 = s_h[cur][b][k], h2 = s_h[cur][b + 8][k];
                i1 += w.x * h1; f1 += w.y * h1; g1 += w.z * h1; o1 += w.w * h1;
                i2 += w.x * h2; f2 += w.y * h2; g2 += w.z * h2; o2 += w.w * h2;
            }
            const float cn1 = fast_sig(f1) * c1 + fast_sig(i1) * fast_tanh(g1);
            const float cn2 = fast_sig(f2) * c2 + fast_sig(i2) * fast_tanh(g2);
            c1 = cn1; c2 = cn2;
            s_h[cur ^ 1][b][j]     = fast_sig(o1) * fast_tanh(cn1);
            s_h[cur ^ 1][b + 8][j] = fast_sig(o2) * fast_tanh(cn2);
        }
        __syncthreads();

        // ---- C: z1 = relu([h_new|se]@Wf1.T + bf1)
        if (t < 240) {
            const int j = t % ND, b = t / ND;
            const float base = s_bf1[j] + se * s_Wf1T[ND * ND + j];
            float a1 = base, a2 = base;
            const float* hn1 = &s_h[cur ^ 1][b][0];
            const float* hn2 = &s_h[cur ^ 1][b + 8][0];
            #pragma unroll
            for (int k = 0; k < ND; ++k) {
                float w = s_Wf1T[k * ND + j];
                a1 += w * hn1[k]; a2 += w * hn2[k];
            }
            z1[b * ND + j]       = fmaxf(a1, 0.0f);
            z1[(b + 8) * ND + j] = fmaxf(a2, 0.0f);
        }
        __syncthreads();

        // ---- D: z2 = relu(z1@Wf2.T + bf2)
        if (t < 240) {
            const int j = t % 15, b = t / 15;
            float a = s_bf2[j];
            #pragma unroll
            for (int k = 0; k < ND; ++k) a += s_Wf2T[k * 15 + j] * z1[b * ND + k];
            z2[b * 15 + j] = fmaxf(a, 0.0f);
        }
        __syncthreads();

        // ---- E: out = z2@Wf3.T + bf3; rin_next = [y[:,i,1:4], out]
        if (t < MB) {
            const int b = t;
            float o = s_bf3;
            #pragma unroll
            for (int k = 0; k < 15; ++k) o += s_Wf3[k] * z2[b * 15 + k];
            out[(long)(i - 1) * NB + b0 + b] = o;
            const float* yb = y + (long)(b0 + b) * (NT * NDIN) + i * NDIN;
            x[b * 34 + 0] = yb[1];
            x[b * 34 + 1] = yb[2];
            x[b * 34 + 2] = yb[3];
            x[b * 34 + 3] = o;
        }
        __syncthreads();
        cur ^= 1;
    }
}

extern "C" void kernel_launch(void* const* d_in, const int* in_sizes, int n_in,
                              void* d_out, int out_size, void* d_ws, size_t ws_size,
                              hipStream_t stream) {
    (void)in_sizes; (void)n_in; (void)out_size; (void)d_ws; (void)ws_size;
    // setup_inputs order: 0 batch_ids, 1 y, 2 encoder_outputs, 3 hidden,
    // 4 Wq, 5 bq, 6 Wk, 7 bk, 8 Wv, 9 bv, 10 Wsa1, 11 bsa1, 12 Wsa2, 13 bsa2,
    // 14 Wg, 15 bg, 16 Wf1, 17 bf1, 18 Wf2, 19 bf2, 20 Wf3, 21 bf3,
    // 22 W_ih, 23 b_ih, 24 W_hh, 25 b_hh.  (Wq/bq/Wk/bk/Wsa* dead: softmax(1)==1)
    const float* y   = (const float*)d_in[1];
    const float* enc = (const float*)d_in[2];
    const float* hid = (const float*)d_in[3];
    const float* Wv  = (const float*)d_in[8];
    const float* bv  = (const float*)d_in[9];
    const float* Wg  = (const float*)d_in[14];
    const float* bg  = (const float*)d_in[15];
    const float* Wf1 = (const float*)d_in[16];
    const float* bf1 = (const float*)d_in[17];
    const float* Wf2 = (const float*)d_in[18];
    const float* bf2 = (const float*)d_in[19];
    const float* Wf3 = (const float*)d_in[20];
    const float* bf3 = (const float*)d_in[21];
    const float* Wih = (const float*)d_in[22];
    const float* bih = (const float*)d_in[23];
    const float* Whh = (const float*)d_in[24];
    const float* bhh = (const float*)d_in[25];
    float* out = (float*)d_out;

    decoder_kernel<<<dim3(NB / MB), dim3(256), 0, stream>>>(
        y, enc, hid, Wv, bv, Wg, bg, Wf1, bf1, Wf2, bf2, Wf3, bf3,
        Wih, bih, Whh, bhh, out);
}

// Round 3
// 139.183 us; speedup vs baseline: 16.4179x; 1.2491x over previous
//
#include <hip/hip_runtime.h>
#include <math.h>

#define NB 16384

__device__ __forceinline__ float fast_sig(float v) { return __builtin_amdgcn_rcpf(1.0f + __expf(-v)); }
__device__ __forceinline__ float fast_tanh(float v) { return 1.0f - 2.0f * __builtin_amdgcn_rcpf(1.0f + __expf(2.0f * v)); }
#define WBAR() __builtin_amdgcn_wave_barrier()
#define LD4(p) (*(const float4*)(p))

// per-wave state: es (phase1) unions with {V,x} (decode). 2176 B, wave-private.
struct WU { union { float es[8 * 60]; struct { float V[8 * 32]; float x[8 * 36]; } d; }; };
// WvT (phase1) unions with the h double-buffers (decode). 8192 B.
union HU { float WvT[60 * 30]; float h[4][2][8 * 32]; };

__global__ __launch_bounds__(256, 2) void decoder_kernel(
    const float* __restrict__ y,      // [B,13,4]
    const float* __restrict__ enc,    // [48,B,60]
    const float* __restrict__ hidden, // [B,30]
    const float* __restrict__ Wv, const float* __restrict__ bv,
    const float* __restrict__ Wg, const float* __restrict__ bg,
    const float* __restrict__ Wf1, const float* __restrict__ bf1,
    const float* __restrict__ Wf2, const float* __restrict__ bf2,
    const float* __restrict__ Wf3, const float* __restrict__ bf3,
    const float* __restrict__ Wih, const float* __restrict__ bih,
    const float* __restrict__ Whh, const float* __restrict__ bhh,
    float* __restrict__ out)          // [12,B]
{
    // weights, k-padded so every activation read is a b128 chunk (pad w = 0)
    __shared__ __align__(16) float4 s_W4[68 * 30];  // [k][j]->(i,f,g,o); k:0..33 x (34,35 z), 36..65 h (66,67 z)
    __shared__ float s_WgT[64 * 30];                // [k][j]; k:0..29 h (30,31 z), 32..61 V (62,63 z)
    __shared__ float s_Wf1T[32 * 30];               // [k][j]; k:0..29 h, 30 = se col, 31 z
    __shared__ float s_Wf2T[32 * 15];               // [k][j2]; 30,31 z
    __shared__ float s_Wf3[16];
    __shared__ __align__(16) float4 s_b4[30];       // (b_ih+b_hh) per gate
    __shared__ float s_bg[32], s_bf1[32], s_bf2[16], s_bv[32];
    __shared__ float s_bf3v;
    __shared__ __align__(16) HU s_hu;
    __shared__ __align__(16) WU s_wu[4];

    const int t = threadIdx.x;
    const int lane = t & 63, wid = t >> 6;
    const int j = lane & 31, rg = lane >> 5;
    const int r0 = rg * 4;
    const int bw = blockIdx.x * 32 + wid * 8;   // wave's first batch row
    WU& W = s_wu[wid];

    // ---------- phase 1a: es accumulation (coalesced float4, BW-bound) ----------
    float ax0=0,ay0=0,az0=0,aw0=0, ax1=0,ay1=0,az1=0,aw1=0;
    {
        const float4* e4 = (const float4*)enc;
        const size_t base = (size_t)bw * 15;
        #pragma unroll 4
        for (int l = 0; l < 48; ++l) {
            const size_t o = (size_t)l * (NB * 15) + base;
            float4 v0 = e4[o + lane];
            ax0 += v0.x; ay0 += v0.y; az0 += v0.z; aw0 += v0.w;
            if (lane < 56) {
                float4 v1 = e4[o + 64 + lane];
                ax1 += v1.x; ay1 += v1.y; az1 += v1.z; aw1 += v1.w;
            }
        }
    }

    // ---------- phase 1b: stage weights (transposed / interleaved / padded) ----------
    for (int d = t; d < 68 * 30; d += 256) {
        const int k = d / 30, jj = d - k * 30;
        float4 w; w.x = w.y = w.z = w.w = 0.f;
        if (k < 34) {
            w.x = Wih[(0*30+jj)*34+k]; w.y = Wih[(1*30+jj)*34+k];
            w.z = Wih[(2*30+jj)*34+k]; w.w = Wih[(3*30+jj)*34+k];
        } else if (k >= 36 && k < 66) {
            const int kk = k - 36;
            w.x = Whh[(0*30+jj)*30+kk]; w.y = Whh[(1*30+jj)*30+kk];
            w.z = Whh[(2*30+jj)*30+kk]; w.w = Whh[(3*30+jj)*30+kk];
        }
        s_W4[d] = w;
    }
    for (int d = t; d < 64 * 30; d += 256) {
        const int k = d / 30, jj = d - k * 30;
        float w = 0.f;
        if (k < 30) w = Wg[jj*60 + k];
        else if (k >= 32 && k < 62) w = Wg[jj*60 + 30 + (k - 32)];
        s_WgT[d] = w;
    }
    for (int d = t; d < 32 * 30; d += 256) {
        const int k = d / 30, jj = d - k * 30;
        s_Wf1T[d] = (k <= 30) ? Wf1[jj*31 + k] : 0.f;
    }
    for (int d = t; d < 32 * 15; d += 256) {
        const int k = d / 15, jj = d - k * 15;
        s_Wf2T[d] = (k < 30) ? Wf2[jj*30 + k] : 0.f;
    }
    for (int d = t; d < 60 * 30; d += 256) {
        const int e = d / 30, jj = d - e * 30;
        s_hu.WvT[d] = Wv[jj*60 + e];
    }
    if (t < 30) {
        float4 b;
        b.x = bih[0*30+t] + bhh[0*30+t]; b.y = bih[1*30+t] + bhh[1*30+t];
        b.z = bih[2*30+t] + bhh[2*30+t]; b.w = bih[3*30+t] + bhh[3*30+t];
        s_b4[t] = b;
        s_bg[t] = bg[t]; s_bf1[t] = bf1[t]; s_bv[t] = bv[t];
    }
    if (t < 15) { s_bf2[t] = bf2[t]; s_Wf3[t] = Wf3[t]; }
    if (t == 0) { s_bf3v = bf3[0]; s_Wf3[15] = 0.f; }

    // write es to own-wave LDS
    {
        const float s = 1.0f / 48.0f;
        float4* esp = (float4*)W.es;
        float4 r; r.x = ax0*s; r.y = ay0*s; r.z = az0*s; r.w = aw0*s;
        esp[lane] = r;
        if (lane < 56) { float4 q; q.x = ax1*s; q.y = ay1*s; q.z = az1*s; q.w = aw1*s; esp[64 + lane] = q; }
    }
    __syncthreads();   // weights + WvT + all es visible

    // ---------- V = es @ Wv.T + bv (softmax over singleton axis == 1 -> context = V) ----------
    float v0 = 0, v1 = 0, v2 = 0, v3 = 0;
    if (j < 30) {
        v0 = v1 = v2 = v3 = s_bv[j];
        const float* e0 = W.es + (r0 + 0) * 60;
        const float* e1 = W.es + (r0 + 1) * 60;
        const float* e2 = W.es + (r0 + 2) * 60;
        const float* e3 = W.es + (r0 + 3) * 60;
        #pragma unroll 6
        for (int e = 0; e < 60; ++e) {
            const float w = s_hu.WvT[e*30 + j];
            v0 += w * e0[e]; v1 += w * e1[e]; v2 += w * e2[e]; v3 += w * e3[e];
        }
    }
    __syncthreads();   // all waves done reading WvT -> safe to overwrite with h

    if (j < 30) {       // V over dead es head (own wave, in-order)
        W.d.V[(r0+0)*32 + j] = v0; W.d.V[(r0+1)*32 + j] = v1;
        W.d.V[(r0+2)*32 + j] = v2; W.d.V[(r0+3)*32 + j] = v3;
    }
    for (int u = lane; u < 240; u += 64) {          // h0 over dead WvT
        const int r = u / 30, c = u - r * 30;
        s_hu.h[wid][0][r*32 + c] = hidden[(size_t)bw*30 + u];
    }
    if (lane < 32) {    // rin0 = nan_to_num(y[:,0,:])
        const int row = lane >> 2, d = lane & 3;
        const float vv = y[(size_t)(bw + row)*52 + d];
        W.d.x[row*36 + d] = (vv == vv) ? vv : 0.f;
    }
    if (lane < 8) W.d.x[lane*36 + 35] = 0.f;        // permanent zero pad
    WBAR();

    // ---------- 12-step recurrence: wave-private, ZERO block barriers ----------
    float c0 = 0, c1 = 0, c2 = 0, c3 = 0;
    int cur = 0;
    #pragma unroll 1
    for (int i = 1; i <= 12; ++i) {
        const float se = (float)i * (1.0f / 12.0f);
        float* __restrict__ hcur = s_hu.h[wid][cur];
        float* __restrict__ hnew = s_hu.h[wid][cur ^ 1];

        // ---- A: gate = sig([h|V]@Wg.T+bg); enh -> x[:,4+j]
        if (j < 30) {
            float a0 = s_bg[j], a1 = a0, a2 = a0, a3 = a0;
            #pragma unroll
            for (int kc = 0; kc < 8; ++kc) {
                const int k = kc * 4;
                const float w0 = s_WgT[(k+0)*30+j], w1 = s_WgT[(k+1)*30+j],
                            w2 = s_WgT[(k+2)*30+j], w3 = s_WgT[(k+3)*30+j];
                const float4 h0 = LD4(&hcur[(r0+0)*32+k]), h1 = LD4(&hcur[(r0+1)*32+k]);
                const float4 h2 = LD4(&hcur[(r0+2)*32+k]), h3 = LD4(&hcur[(r0+3)*32+k]);
                a0 += w0*h0.x + w1*h0.y + w2*h0.z + w3*h0.w;
                a1 += w0*h1.x + w1*h1.y + w2*h1.z + w3*h1.w;
                a2 += w0*h2.x + w1*h2.y + w2*h2.z + w3*h2.w;
                a3 += w0*h3.x + w1*h3.y + w2*h3.z + w3*h3.w;
            }
            #pragma unroll
            for (int kc = 0; kc < 8; ++kc) {
                const int k = kc * 4;
                const float w0 = s_WgT[(32+k+0)*30+j], w1 = s_WgT[(32+k+1)*30+j],
                            w2 = s_WgT[(32+k+2)*30+j], w3 = s_WgT[(32+k+3)*30+j];
                const float4 q0 = LD4(&W.d.V[(r0+0)*32+k]), q1 = LD4(&W.d.V[(r0+1)*32+k]);
                const float4 q2 = LD4(&W.d.V[(r0+2)*32+k]), q3 = LD4(&W.d.V[(r0+3)*32+k]);
                a0 += w0*q0.x + w1*q0.y + w2*q0.z + w3*q0.w;
                a1 += w0*q1.x + w1*q1.y + w2*q1.z + w3*q1.w;
                a2 += w0*q2.x + w1*q2.y + w2*q2.z + w3*q2.w;
                a3 += w0*q3.x + w1*q3.y + w2*q3.z + w3*q3.w;
            }
            const float g0 = fast_sig(a0), g1 = fast_sig(a1), g2 = fast_sig(a2), g3 = fast_sig(a3);
            W.d.x[(r0+0)*36+4+j] = g0*hcur[(r0+0)*32+j] + (1.f-g0)*W.d.V[(r0+0)*32+j];
            W.d.x[(r0+1)*36+4+j] = g1*hcur[(r0+1)*32+j] + (1.f-g1)*W.d.V[(r0+1)*32+j];
            W.d.x[(r0+2)*36+4+j] = g2*hcur[(r0+2)*32+j] + (1.f-g2)*W.d.V[(r0+2)*32+j];
            W.d.x[(r0+3)*36+4+j] = g3*hcur[(r0+3)*32+j] + (1.f-g3)*W.d.V[(r0+3)*32+j];
        }
        WBAR();

        // ---- B: LSTM. 16 accumulator chains, b128 weights (gate-interleaved)
        if (j < 30) {
            const float4 bb = s_b4[j];
            float i0=bb.x, f0=bb.y, g0=bb.z, o0=bb.w;
            float i1=bb.x, f1=bb.y, g1=bb.z, o1=bb.w;
            float i2=bb.x, f2=bb.y, g2=bb.z, o2=bb.w;
            float i3=bb.x, f3=bb.y, g3=bb.z, o3=bb.w;
#define LSTM_CHUNK(WK, D0, D1, D2, D3)                                              \
            {                                                                        \
                const float4 wA = s_W4[(WK+0)*30+j], wB = s_W4[(WK+1)*30+j],         \
                             wC = s_W4[(WK+2)*30+j], wD = s_W4[(WK+3)*30+j];         \
                const float4 d0 = D0, d1 = D1, d2 = D2, d3 = D3;                     \
                i0 += wA.x*d0.x + wB.x*d0.y + wC.x*d0.z + wD.x*d0.w;                 \
                f0 += wA.y*d0.x + wB.y*d0.y + wC.y*d0.z + wD.y*d0.w;                 \
                g0 += wA.z*d0.x + wB.z*d0.y + wC.z*d0.z + wD.z*d0.w;                 \
                o0 += wA.w*d0.x + wB.w*d0.y + wC.w*d0.z + wD.w*d0.w;                 \
                i1 += wA.x*d1.x + wB.x*d1.y + wC.x*d1.z + wD.x*d1.w;                 \
                f1 += wA.y*d1.x + wB.y*d1.y + wC.y*d1.z + wD.y*d1.w;                 \
                g1 += wA.z*d1.x + wB.z*d1.y + wC.z*d1.z + wD.z*d1.w;                 \
                o1 += wA.w*d1.x + wB.w*d1.y + wC.w*d1.z + wD.w*d1.w;                 \
                i2 += wA.x*d2.x + wB.x*d2.y + wC.x*d2.z + wD.x*d2.w;                 \
                f2 += wA.y*d2.x + wB.y*d2.y + wC.y*d2.z + wD.y*d2.w;                 \
                g2 += wA.z*d2.x + wB.z*d2.y + wC.z*d2.z + wD.z*d2.w;                 \
                o2 += wA.w*d2.x + wB.w*d2.y + wC.w*d2.z + wD.w*d2.w;                 \
                i3 += wA.x*d3.x + wB.x*d3.y + wC.x*d3.z + wD.x*d3.w;                 \
                f3 += wA.y*d3.x + wB.y*d3.y + wC.y*d3.z + wD.y*d3.w;                 \
                g3 += wA.z*d3.x + wB.z*d3.y + wC.z*d3.z + wD.z*d3.w;                 \
                o3 += wA.w*d3.x + wB.w*d3.y + wC.w*d3.z + wD.w*d3.w;                 \
            }
            #pragma unroll
            for (int kc = 0; kc < 9; ++kc) {     // x part (k 0..35; w34,35 = 0, x35 = 0)
                const int k = kc * 4;
                LSTM_CHUNK(k, LD4(&W.d.x[(r0+0)*36+k]), LD4(&W.d.x[(r0+1)*36+k]),
                              LD4(&W.d.x[(r0+2)*36+k]), LD4(&W.d.x[(r0+3)*36+k]))
            }
            #pragma unroll
            for (int kc = 0; kc < 8; ++kc) {     // h part (k 0..31; w30,31 = 0)
                const int k = kc * 4;
                LSTM_CHUNK(36+k, LD4(&hcur[(r0+0)*32+k]), LD4(&hcur[(r0+1)*32+k]),
                                 LD4(&hcur[(r0+2)*32+k]), LD4(&hcur[(r0+3)*32+k]))
            }
#undef LSTM_CHUNK
            const float cn0 = fast_sig(f0)*c0 + fast_sig(i0)*fast_tanh(g0); c0 = cn0;
            const float cn1 = fast_sig(f1)*c1 + fast_sig(i1)*fast_tanh(g1); c1 = cn1;
            const float cn2 = fast_sig(f2)*c2 + fast_sig(i2)*fast_tanh(g2); c2 = cn2;
            const float cn3 = fast_sig(f3)*c3 + fast_sig(i3)*fast_tanh(g3); c3 = cn3;
            hnew[(r0+0)*32+j] = fast_sig(o0)*fast_tanh(cn0);
            hnew[(r0+1)*32+j] = fast_sig(o1)*fast_tanh(cn1);
            hnew[(r0+2)*32+j] = fast_sig(o2)*fast_tanh(cn2);
            hnew[(r0+3)*32+j] = fast_sig(o3)*fast_tanh(cn3);
        } else {
            // lanes j=30/31 maintain the pad cols: [30]=se (fc1 folds se in), [31]=0
            const float pv = (j == 30) ? se : 0.f;
            hnew[(r0+0)*32+j] = pv; hnew[(r0+1)*32+j] = pv;
            hnew[(r0+2)*32+j] = pv; hnew[(r0+3)*32+j] = pv;
        }
        WBAR();

        // prefetch next rin's y components (consumed in E; latency hides under C/D)
        float py1 = 0, py2 = 0, py3 = 0;
        if (lane < 8) {
            const float* yp = y + (size_t)(bw + lane)*52 + i*4;
            py1 = yp[1]; py2 = yp[2]; py3 = yp[3];
        }

        // ---- C: z1 = relu([h_new|se]@Wf1.T+bf1); z1 aliases dead old-h buffer
        float* __restrict__ z1 = hcur;
        if (j < 30) {
            float a0 = s_bf1[j], a1 = a0, a2 = a0, a3 = a0;
            #pragma unroll
            for (int kc = 0; kc < 8; ++kc) {      // k=28 chunk reads [28,29,se,0]
                const int k = kc * 4;
                const float w0 = s_Wf1T[(k+0)*30+j], w1 = s_Wf1T[(k+1)*30+j],
                            w2 = s_Wf1T[(k+2)*30+j], w3 = s_Wf1T[(k+3)*30+j];
                const float4 h0 = LD4(&hnew[(r0+0)*32+k]), h1 = LD4(&hnew[(r0+1)*32+k]);
                const float4 h2 = LD4(&hnew[(r0+2)*32+k]), h3 = LD4(&hnew[(r0+3)*32+k]);
                a0 += w0*h0.x + w1*h0.y + w2*h0.z + w3*h0.w;
                a1 += w0*h1.x + w1*h1.y + w2*h1.z + w3*h1.w;
                a2 += w0*h2.x + w1*h2.y + w2*h2.z + w3*h2.w;
                a3 += w0*h3.x + w1*h3.y + w2*h3.z + w3*h3.w;
            }
            z1[(r0+0)*32+j] = fmaxf(a0, 0.f); z1[(r0+1)*32+j] = fmaxf(a1, 0.f);
            z1[(r0+2)*32+j] = fmaxf(a2, 0.f); z1[(r0+3)*32+j] = fmaxf(a3, 0.f);
        }
        WBAR();

        // ---- D: z2 = relu(z1@Wf2.T+bf2) -> x[:,20..34] (dead enh space)
        if (j < 30) {
            const int j2 = (j < 15) ? j : (j - 15);
            const int ra = r0 + ((j < 15) ? 0 : 2);
            float a0 = s_bf2[j2], a1 = a0;
            #pragma unroll
            for (int kc = 0; kc < 8; ++kc) {      // z1 pad cols hit w=0
                const int k = kc * 4;
                const float w0 = s_Wf2T[(k+0)*15+j2], w1 = s_Wf2T[(k+1)*15+j2],
                            w2 = s_Wf2T[(k+2)*15+j2], w3 = s_Wf2T[(k+3)*15+j2];
                const float4 z0 = LD4(&z1[(ra+0)*32+k]), zz = LD4(&z1[(ra+1)*32+k]);
                a0 += w0*z0.x + w1*z0.y + w2*z0.z + w3*z0.w;
                a1 += w0*zz.x + w1*zz.y + w2*zz.z + w3*zz.w;
            }
            W.d.x[(ra+0)*36+20+j2] = fmaxf(a0, 0.f);
            W.d.x[(ra+1)*36+20+j2] = fmaxf(a1, 0.f);
        }
        WBAR();

        // ---- E: out = z2@Wf3.T+bf3; rin_next = [y[:,i,1:4], out]
        if (lane < 8) {
            float o = s_bf3v;
            #pragma unroll
            for (int k = 0; k < 15; ++k) o += s_Wf3[k] * W.d.x[lane*36+20+k];
            out[(size_t)(i-1)*NB + bw + lane] = o;
            W.d.x[lane*36+0] = py1; W.d.x[lane*36+1] = py2;
            W.d.x[lane*36+2] = py3; W.d.x[lane*36+3] = o;
        }
        WBAR();
        cur ^= 1;
    }
}

extern "C" void kernel_launch(void* const* d_in, const int* in_sizes, int n_in,
                              void* d_out, int out_size, void* d_ws, size_t ws_size,
                              hipStream_t stream) {
    (void)in_sizes; (void)n_in; (void)out_size; (void)d_ws; (void)ws_size;
    // 0 batch_ids, 1 y, 2 encoder_outputs, 3 hidden, 4 Wq, 5 bq, 6 Wk, 7 bk,
    // 8 Wv, 9 bv, 10 Wsa1, 11 bsa1, 12 Wsa2, 13 bsa2, 14 Wg, 15 bg,
    // 16 Wf1, 17 bf1, 18 Wf2, 19 bf2, 20 Wf3, 21 bf3, 22 W_ih, 23 b_ih,
    // 24 W_hh, 25 b_hh.  (Wq/bq/Wk/bk/Wsa* dead: softmax over size-1 axis == 1)
    const float* y   = (const float*)d_in[1];
    const float* enc = (const float*)d_in[2];
    const float* hid = (const float*)d_in[3];
    decoder_kernel<<<dim3(NB / 32), dim3(256), 0, stream>>>(
        y, enc, hid,
        (const float*)d_in[8],  (const float*)d_in[9],
        (const float*)d_in[14], (const float*)d_in[15],
        (const float*)d_in[16], (const float*)d_in[17],
        (const float*)d_in[18], (const float*)d_in[19],
        (const float*)d_in[20], (const float*)d_in[21],
        (const float*)d_in[22], (const float*)d_in[23],
        (const float*)d_in[24], (const float*)d_in[25],
        (float*)d_out);
}